// Round 3
// baseline (662.840 us; speedup 1.0000x reference)
//
#include <hip/hip_runtime.h>
#include <hip/hip_bf16.h>
#include <math.h>

#define NE 8
#define MM 2048
#define DH 1024   // hidden
#define DI 4096   // intermediate

#define BK  32
#define LDA 40    // padded LDS stride for manually-staged fp32 tiles

typedef short bf16x8 __attribute__((ext_vector_type(8)));
typedef float f32x4  __attribute__((ext_vector_type(4)));

__device__ __forceinline__ unsigned short f2bf(float f) {
    unsigned u = __builtin_bit_cast(unsigned, f);
    u += 0x7FFFu + ((u >> 16) & 1u);   // round-to-nearest-even
    return (unsigned short)(u >> 16);
}

// async global(16B/lane) -> LDS. lds ptr must be wave-uniform base; HW adds lane*16.
__device__ __forceinline__ void gload_lds16(const void* g, void* l) {
    __builtin_amdgcn_global_load_lds(
        (__attribute__((address_space(1))) void*)g,
        (__attribute__((address_space(3))) void*)l, 16, 0, 0);
}

// Fast exact-erf GELU: Abramowitz&Stegun 7.1.26, max abs err 1.5e-7 (<< bf16 ulp).
__device__ __forceinline__ float gelu_fast(float x) {
    float z = fabsf(x) * 0.70710678118654752f;
    float t = __builtin_amdgcn_rcpf(1.0f + 0.3275911f * z);
    float p = t * (0.254829592f + t * (-0.284496736f + t * (1.421413741f +
              t * (-1.453152027f + t * 1.061405429f))));
    float er = 1.0f - p * __expf(-z * z);
    er = (x < 0.0f) ? -er : er;
    return 0.5f * x * (1.0f + er);
}

// ---------------- elementwise fp32 -> bf16 (for X)
__global__ __launch_bounds__(256)
void convert_bf16(const float* __restrict__ in, unsigned short* __restrict__ out,
                  long long n)   // n multiple of 8*256
{
    long long i = ((long long)blockIdx.x * 256 + threadIdx.x) * 8;
    const float4 v0 = *(const float4*)(in + i);
    const float4 v1 = *(const float4*)(in + i + 4);
    bf16x8 s;
    s[0] = (short)f2bf(v0.x); s[1] = (short)f2bf(v0.y);
    s[2] = (short)f2bf(v0.z); s[3] = (short)f2bf(v0.w);
    s[4] = (short)f2bf(v1.x); s[5] = (short)f2bf(v1.y);
    s[6] = (short)f2bf(v1.z); s[7] = (short)f2bf(v1.w);
    *(bf16x8*)(out + i) = s;
}

// ---------------- weight transpose+convert: fp32 [K,N] -> bf16 [N,K], per expert
__global__ __launch_bounds__(256)
void transpose_bf16(const float* __restrict__ in, unsigned short* __restrict__ out,
                    int K, int N)
{
    __shared__ short tile[64][66];
    const int e  = blockIdx.z;
    const int n0 = blockIdx.x * 64;
    const int k0 = blockIdx.y * 64;
    const float* ine = in + (size_t)e * K * N;
    unsigned short* oute = out + (size_t)e * N * K;
    const int tid = threadIdx.x;

    #pragma unroll
    for (int i = 0; i < 4; ++i) {
        int idx = tid + i * 256;
        int r  = idx >> 4;
        int c  = (idx & 15) * 4;
        const float4 v = *(const float4*)(ine + (size_t)(k0 + r) * N + n0 + c);
        tile[r][c + 0] = (short)f2bf(v.x);
        tile[r][c + 1] = (short)f2bf(v.y);
        tile[r][c + 2] = (short)f2bf(v.z);
        tile[r][c + 3] = (short)f2bf(v.w);
    }
    __syncthreads();
    #pragma unroll
    for (int i = 0; i < 4; ++i) {
        int idx = tid + i * 256;
        int n  = idx >> 4;
        int k  = (idx & 15) * 4;
        short4 s;
        s.x = tile[k + 0][n];
        s.y = tile[k + 1][n];
        s.z = tile[k + 2][n];
        s.w = tile[k + 3][n];
        *(short4*)(oute + (size_t)(n0 + n) * K + k0 + k) = s;
    }
}

// ================= v4: 256x256 tile, 512 thr (8 waves 2Mx4N), m201-style
// 8-phase pipeline: per phase {ds-load subtile, 1 half-tile stage, barrier,
// lgkm0, 16 MFMA (setprio), barrier}; vmcnt(2) only at ph3/ph7.
//
// Per K-tile (K=64), 4 phases (mh,ks) = (0,0),(1,0),(0,1),(1,1):
//   B-ks fragments loaded once per ks, kept in regs for both mh phases ->
//   LDS reads stay at the minimal 24 b128/wave/K-tile.
// Half-tile liveness (per buffer): A0,B0,B1 last read at phase 2; A1 at 3.
// Stage slots (iter i = tiles 2i(buf0, ph0-3) + 2i+1(buf1, ph4-7)):
//   ph0: B1(2i+1)->buf1   ph1: A0(2i+1)->buf1   ph2: A1(2i+1)->buf1
//   ph3: B0(2i+2)->buf0   ph4: B1(2i+2)->buf0   ph5: A0(2i+2)->buf0
//   ph6: A1(2i+2)->buf0   ph7: B0(2i+3)->buf1
// Each stage targets a region whose last reader drained >=1 barrier earlier.
// vmcnt(2) at ph3-end: only ph3's own 2 loads younger -> buf1(2i+1) landed.
// vmcnt(2) at ph7-end: only ph7's own 2 loads younger -> buf0(2i+2) landed.

#define VMC(n)  asm volatile("s_waitcnt vmcnt(" #n ")" ::: "memory")
#define LGKM0   do { asm volatile("s_waitcnt lgkmcnt(0)" ::: "memory"); \
                     __builtin_amdgcn_sched_barrier(0); } while (0)
#define BARX    do { __builtin_amdgcn_s_barrier(); \
                     __builtin_amdgcn_sched_barrier(0); } while (0)
#define PRIO1   __builtin_amdgcn_s_setprio(1)
#define PRIO0   __builtin_amdgcn_s_setprio(0)

// stage rows [half*128, half*128+128) of 256x64 bf16 tile t (2 instr/thread).
// Linear LDS dest; inverse-swizzled global source (rule #21).
#define STAGE_H(Ptr, r0, s, t, KD, Dst, half)                                  \
    { const size_t kk = (size_t)(t) * 64;                                      \
      _Pragma("unroll")                                                        \
      for (int j = 0; j < 2; ++j) {                                            \
          int idx = tid + j * 512;                                             \
          int row = (half) * 128 + (idx >> 3);                                 \
          int gs  = (idx & 7) ^ (row & 7);                                     \
          gload_lds16(Ptr + (size_t)((r0) + row) * (KD) + kk + gs * 8,         \
                      &Dst[s][((half) * 1024 + j * 512 + wave * 64) * 8]); } }

#define LOAD_B_KS(s, ks)                                                       \
    _Pragma("unroll")                                                          \
    for (int ni = 0; ni < 4; ++ni)                                             \
        b[ni] = *(const bf16x8*)(&Bs[s][(wn4 * 64 + ni * 16 + lr) * 64 +       \
                      ((((ks) * 4 + lq) ^ (lr & 7)) * 8)]);

#define LOAD_A_HK(s, mh, ks)                                                   \
    _Pragma("unroll")                                                          \
    for (int mi = 0; mi < 4; ++mi)                                             \
        a[mi] = *(const bf16x8*)(&As[s][(wm2 * 128 + (mh) * 64 + mi * 16 + lr) * 64 + \
                      ((((ks) * 4 + lq) ^ (lr & 7)) * 8)]);

#define MFMA16(mh)                                                             \
    _Pragma("unroll")                                                          \
    for (int mi = 0; mi < 4; ++mi)                                             \
        _Pragma("unroll")                                                      \
        for (int ni = 0; ni < 4; ++ni)                                         \
            acc[(mh) * 4 + mi][ni] = __builtin_amdgcn_mfma_f32_16x16x32_bf16(  \
                a[mi], b[ni], acc[(mh) * 4 + mi][ni], 0, 0, 0);

#define PIPE_BODY_V4(KD)                                                       \
    __shared__ short As[2][256 * 64];                                          \
    __shared__ short Bs[2][256 * 64];                                          \
    const int tid  = threadIdx.x;                                              \
    const int lane = tid & 63;                                                 \
    const int wave = tid >> 6;                                                 \
    const int wm2  = wave >> 2;                                                \
    const int wn4  = wave & 3;                                                 \
    const int lr   = lane & 15;                                                \
    const int lq   = lane >> 4;                                                \
    const int ITERS = (KD) / 128;                                              \
    f32x4 acc[8][4] = {};                                                      \
    bf16x8 a[4], b[4];                                                         \
    STAGE_H(Ae, m0, 0, 0, KD, As, 0); STAGE_H(Ae, m0, 0, 0, KD, As, 1);        \
    STAGE_H(Be, n0, 0, 0, KD, Bs, 0); STAGE_H(Be, n0, 0, 0, KD, Bs, 1);        \
    STAGE_H(Be, n0, 1, 1, KD, Bs, 0);                                          \
    VMC(2); BARX;                                                              \
    _Pragma("unroll 1")                                                        \
    for (int i = 0; i < ITERS; ++i) {                                          \
        const bool nl = (i < ITERS - 1);                                       \
        /* ph0: buf0 (mh0,ks0) */                                              \
        LOAD_B_KS(0, 0); LOAD_A_HK(0, 0, 0);                                   \
        STAGE_H(Be, n0, 1, 2 * i + 1, KD, Bs, 1);                              \
        BARX; LGKM0; PRIO1; MFMA16(0); PRIO0; BARX;                            \
        /* ph1: buf0 (mh1,ks0) */                                              \
        LOAD_A_HK(0, 1, 0);                                                    \
        STAGE_H(Ae, m0, 1, 2 * i + 1, KD, As, 0);                              \
        BARX; LGKM0; PRIO1; MFMA16(1); PRIO0; BARX;                            \
        /* ph2: buf0 (mh0,ks1) */                                              \
        LOAD_B_KS(0, 1); LOAD_A_HK(0, 0, 1);                                   \
        STAGE_H(Ae, m0, 1, 2 * i + 1, KD, As, 1);                              \
        BARX; LGKM0; PRIO1; MFMA16(0); PRIO0; BARX;                            \
        /* ph3: buf0 (mh1,ks1) */                                              \
        LOAD_A_HK(0, 1, 1);                                                    \
        if (nl) STAGE_H(Be, n0, 0, 2 * i + 2, KD, Bs, 0);                      \
        BARX; LGKM0; PRIO1; MFMA16(1); PRIO0;                                  \
        if (nl) { VMC(2); } else { VMC(0); }                                   \
        BARX;                                                                  \
        /* ph4: buf1 (mh0,ks0) */                                              \
        LOAD_B_KS(1, 0); LOAD_A_HK(1, 0, 0);                                   \
        if (nl) STAGE_H(Be, n0, 0, 2 * i + 2, KD, Bs, 1);                      \
        BARX; LGKM0; PRIO1; MFMA16(0); PRIO0; BARX;                            \
        /* ph5: buf1 (mh1,ks0) */                                              \
        LOAD_A_HK(1, 1, 0);                                                    \
        if (nl) STAGE_H(Ae, m0, 0, 2 * i + 2, KD, As, 0);                      \
        BARX; LGKM0; PRIO1; MFMA16(1); PRIO0; BARX;                            \
        /* ph6: buf1 (mh0,ks1) */                                              \
        LOAD_B_KS(1, 1); LOAD_A_HK(1, 0, 1);                                   \
        if (nl) STAGE_H(Ae, m0, 0, 2 * i + 2, KD, As, 1);                      \
        BARX; LGKM0; PRIO1; MFMA16(0); PRIO0; BARX;                            \
        /* ph7: buf1 (mh1,ks1) */                                              \
        LOAD_A_HK(1, 1, 1);                                                    \
        if (nl) STAGE_H(Be, n0, 1, 2 * i + 3, KD, Bs, 0);                      \
        BARX; LGKM0; PRIO1; MFMA16(1); PRIO0;                                  \
        if (nl) VMC(2);                                                        \
        BARX;                                                                  \
    }

// XCD-bijective chunked swizzle, m-fastest within expert (1 expert/XCD).
#define DECOMPOSE_XCD_V3(TPE)                                                  \
    const int bsw  = (blockIdx.x & 7) * (TPE) + (blockIdx.x >> 3);             \
    const int e    = bsw / (TPE);                                              \
    const int trem = bsw - e * (TPE);                                          \
    const int m0   = (trem & 7) * 256;                                         \
    const int n0   = (trem >> 3) * 256;

// GEMM1: H = gelu_erf(Xb @ W1t^T); Xb bf16 [M,DH], W1t bf16 [DI,DH], H bf16 [M,DI]
__global__ __launch_bounds__(512, 2)
void gemm1_v4(const unsigned short* __restrict__ Xb,
              const unsigned short* __restrict__ W1t,
              unsigned short* __restrict__ H)
{
    DECOMPOSE_XCD_V3(128)
    const unsigned short* Ae = Xb  + (size_t)e * MM * DH;
    const unsigned short* Be = W1t + (size_t)e * DI * DH;
    unsigned short* He = H + (size_t)e * MM * DI;

    PIPE_BODY_V4(DH)

    #pragma unroll
    for (int mi = 0; mi < 8; ++mi) {
        #pragma unroll
        for (int ni = 0; ni < 4; ++ni) {
            const int col = n0 + wn4 * 64 + ni * 16 + lr;
            #pragma unroll
            for (int r = 0; r < 4; ++r) {
                const int row = m0 + wm2 * 128 + mi * 16 + lq * 4 + r;
                He[(size_t)row * DI + col] = f2bf(gelu_fast(acc[mi][ni][r]));
            }
        }
    }
}

// GEMM2: O = H @ W2t^T; H bf16 [M,DI], W2t bf16 [DH,DI], O fp32 [M,DH]
__global__ __launch_bounds__(512, 2)
void gemm2_v4(const unsigned short* __restrict__ H,
              const unsigned short* __restrict__ W2t,
              float* __restrict__ O)
{
    DECOMPOSE_XCD_V3(32)
    const unsigned short* Ae = H   + (size_t)e * MM * DI;
    const unsigned short* Be = W2t + (size_t)e * DH * DI;
    float* Oe = O + (size_t)e * MM * DH;

    PIPE_BODY_V4(DI)

    #pragma unroll
    for (int mi = 0; mi < 8; ++mi) {
        #pragma unroll
        for (int ni = 0; ni < 4; ++ni) {
            const int col = n0 + wn4 * 64 + ni * 16 + lr;
            #pragma unroll
            for (int r = 0; r < 4; ++r) {
                const int row = m0 + wm2 * 128 + mi * 16 + lq * 4 + r;
                Oe[(size_t)row * DH + col] = acc[mi][ni][r];
            }
        }
    }
}

// ---------------- mid-tier gemm1 (fp32 X manually staged)
__global__ __launch_bounds__(256, 2)
void gemm1_mixed(const float* __restrict__ X, const unsigned short* __restrict__ W1t,
                 unsigned short* __restrict__ H)
{
    __shared__ short As[128 * LDA];
    __shared__ short Bs[128 * 32];
    const int e  = blockIdx.z;
    const int m0 = blockIdx.y * 128;
    const int n0 = blockIdx.x * 128;
    const float* Xe = X + (size_t)e * MM * DH;
    const unsigned short* Bt = W1t + (size_t)e * DI * DH;
    unsigned short* He = H + (size_t)e * MM * DI;
    const int tid  = threadIdx.x;
    const int lane = tid & 63;
    const int wave = tid >> 6;
    const int wm = (wave >> 1) * 64;
    const int wn = (wave &  1) * 64;
    const int lr = lane & 15;
    const int lq = lane >> 4;
    f32x4 acc[4][4] = {};
    for (int k0 = 0; k0 < DH; k0 += BK) {
        #pragma unroll
        for (int i = 0; i < 2; ++i) {
            int idx  = tid + i * 256;
            gload_lds16(Bt + (size_t)(n0 + (idx >> 2)) * DH + k0 + (idx & 3) * 8,
                        Bs + (i * 256 + wave * 64) * 8);
        }
        #pragma unroll
        for (int i = 0; i < 4; ++i) {
            int idx = tid + i * 256;
            int row = idx >> 3;
            int col = (idx & 7) * 4;
            const float4 v = *(const float4*)(Xe + (size_t)(m0 + row) * DH + k0 + col);
            short4 s;
            s.x = (short)f2bf(v.x); s.y = (short)f2bf(v.y);
            s.z = (short)f2bf(v.z); s.w = (short)f2bf(v.w);
            *(short4*)(&As[row * LDA + col]) = s;
        }
        __syncthreads();
        bf16x8 a[4], b[4];
        #pragma unroll
        for (int i = 0; i < 4; ++i)
            a[i] = *(const bf16x8*)(&As[(wm + i * 16 + lr) * LDA + lq * 8]);
        #pragma unroll
        for (int i = 0; i < 4; ++i)
            b[i] = *(const bf16x8*)(&Bs[(wn + i * 16 + lr) * 32 + lq * 8]);
        #pragma unroll
        for (int mi = 0; mi < 4; ++mi)
            #pragma unroll
            for (int ni = 0; ni < 4; ++ni)
                acc[mi][ni] = __builtin_amdgcn_mfma_f32_16x16x32_bf16(a[mi], b[ni], acc[mi][ni], 0, 0, 0);
        __syncthreads();
    }
    #pragma unroll
    for (int mi = 0; mi < 4; ++mi) {
        #pragma unroll
        for (int ni = 0; ni < 4; ++ni) {
            const int col = n0 + wn + ni * 16 + lr;
            #pragma unroll
            for (int r = 0; r < 4; ++r) {
                const int row = m0 + wm + mi * 16 + lq * 4 + r;
                He[(size_t)row * DI + col] = f2bf(gelu_fast(acc[mi][ni][r]));
            }
        }
    }
}

// ================= round-1 fallback (needs only 128MB ws) =================
__global__ __launch_bounds__(256, 2)
void fb_gemm1(const float* __restrict__ X, const float* __restrict__ W1,
              unsigned short* __restrict__ H)
{
    __shared__ short As[128 * LDA];
    __shared__ short Bs[128 * LDA];
    const int e  = blockIdx.z;
    const int m0 = blockIdx.y * 128;
    const int n0 = blockIdx.x * 128;
    const float* Xe  = X  + (size_t)e * MM * DH;
    const float* W1e = W1 + (size_t)e * DH * DI;
    unsigned short* He = H + (size_t)e * MM * DI;
    const int tid  = threadIdx.x;
    const int lane = tid & 63;
    const int wave = tid >> 6;
    const int wm = (wave >> 1) * 64;
    const int wn = (wave &  1) * 64;
    const int lr = lane & 15;
    const int lq = lane >> 4;
    f32x4 acc[4][4] = {};
    for (int k0 = 0; k0 < DH; k0 += BK) {
        #pragma unroll
        for (int i = 0; i < 4; ++i) {
            int idx = tid + i * 256;
            int row = idx >> 3;
            int col = (idx & 7) * 4;
            const float4 v = *(const float4*)(Xe + (size_t)(m0 + row) * DH + k0 + col);
            short4 s;
            s.x = (short)f2bf(v.x); s.y = (short)f2bf(v.y);
            s.z = (short)f2bf(v.z); s.w = (short)f2bf(v.w);
            *(short4*)(&As[row * LDA + col]) = s;
        }
        #pragma unroll
        for (int i = 0; i < 4; ++i) {
            int idx  = tid + i * 256;
            int krow = idx >> 5;
            int ncol = (idx & 31) * 4;
            const float4 v = *(const float4*)(W1e + (size_t)(k0 + krow) * DI + n0 + ncol);
            Bs[(ncol + 0) * LDA + krow] = (short)f2bf(v.x);
            Bs[(ncol + 1) * LDA + krow] = (short)f2bf(v.y);
            Bs[(ncol + 2) * LDA + krow] = (short)f2bf(v.z);
            Bs[(ncol + 3) * LDA + krow] = (short)f2bf(v.w);
        }
        __syncthreads();
        bf16x8 a[4], b[4];
        #pragma unroll
        for (int i = 0; i < 4; ++i)
            a[i] = *(const bf16x8*)(&As[(wm + i * 16 + lr) * LDA + lq * 8]);
        #pragma unroll
        for (int i = 0; i < 4; ++i)
            b[i] = *(const bf16x8*)(&Bs[(wn + i * 16 + lr) * LDA + lq * 8]);
        #pragma unroll
        for (int mi = 0; mi < 4; ++mi)
            #pragma unroll
            for (int ni = 0; ni < 4; ++ni)
                acc[mi][ni] = __builtin_amdgcn_mfma_f32_16x16x32_bf16(a[mi], b[ni], acc[mi][ni], 0, 0, 0);
        __syncthreads();
    }
    #pragma unroll
    for (int mi = 0; mi < 4; ++mi) {
        #pragma unroll
        for (int ni = 0; ni < 4; ++ni) {
            const int col = n0 + wn + ni * 16 + lr;
            #pragma unroll
            for (int r = 0; r < 4; ++r) {
                const int row = m0 + wm + mi * 16 + lq * 4 + r;
                He[(size_t)row * DI + col] = f2bf(gelu_fast(acc[mi][ni][r]));
            }
        }
    }
}

__global__ __launch_bounds__(256, 2)
void fb_gemm2(const unsigned short* __restrict__ H, const float* __restrict__ W2,
              float* __restrict__ O)
{
    __shared__ short As[128 * LDA];
    __shared__ short Bs[128 * LDA];
    const int e  = blockIdx.z;
    const int m0 = blockIdx.y * 128;
    const int n0 = blockIdx.x * 128;
    const unsigned short* He = H + (size_t)e * MM * DI;
    const float* W2e = W2 + (size_t)e * DI * DH;
    float* Oe = O + (size_t)e * MM * DH;
    const int tid  = threadIdx.x;
    const int lane = tid & 63;
    const int wave = tid >> 6;
    const int wm = (wave >> 1) * 64;
    const int wn = (wave &  1) * 64;
    const int lr = lane & 15;
    const int lq = lane >> 4;
    f32x4 acc[4][4] = {};
    for (int k0 = 0; k0 < DI; k0 += BK) {
        #pragma unroll
        for (int i = 0; i < 2; ++i) {
            int idx = tid + i * 256;
            int row = idx >> 2;
            int col = (idx & 3) * 8;
            bf16x8 v = *(const bf16x8*)(He + (size_t)(m0 + row) * DI + k0 + col);
            *(bf16x8*)(&As[row * LDA + col]) = v;
        }
        #pragma unroll
        for (int i = 0; i < 4; ++i) {
            int idx  = tid + i * 256;
            int krow = idx >> 5;
            int ncol = (idx & 31) * 4;
            const float4 v = *(const float4*)(W2e + (size_t)(k0 + krow) * DH + n0 + ncol);
            Bs[(ncol + 0) * LDA + krow] = (short)f2bf(v.x);
            Bs[(ncol + 1) * LDA + krow] = (short)f2bf(v.y);
            Bs[(ncol + 2) * LDA + krow] = (short)f2bf(v.z);
            Bs[(ncol + 3) * LDA + krow] = (short)f2bf(v.w);
        }
        __syncthreads();
        bf16x8 a[4], b[4];
        #pragma unroll
        for (int i = 0; i < 4; ++i)
            a[i] = *(const bf16x8*)(&As[(wm + i * 16 + lr) * LDA + lq * 8]);
        #pragma unroll
        for (int i = 0; i < 4; ++i)
            b[i] = *(const bf16x8*)(&Bs[(wn + i * 16 + lr) * LDA + lq * 8]);
        #pragma unroll
        for (int mi = 0; mi < 4; ++mi)
            #pragma unroll
            for (int ni = 0; ni < 4; ++ni)
                acc[mi][ni] = __builtin_amdgcn_mfma_f32_16x16x32_bf16(a[mi], b[ni], acc[mi][ni], 0, 0, 0);
        __syncthreads();
    }
    #pragma unroll
    for (int mi = 0; mi < 4; ++mi) {
        #pragma unroll
        for (int ni = 0; ni < 4; ++ni) {
            const int col = n0 + wn + ni * 16 + lr;
            #pragma unroll
            for (int r = 0; r < 4; ++r) {
                const int row = m0 + wm + mi * 16 + lq * 4 + r;
                Oe[(size_t)row * DH + col] = acc[mi][ni][r];
            }
        }
    }
}

extern "C" void kernel_launch(void* const* d_in, const int* in_sizes, int n_in,
                              void* d_out, int out_size, void* d_ws, size_t ws_size,
                              hipStream_t stream) {
    const float* x  = (const float*)d_in[0];
    const float* w1 = (const float*)d_in[1];
    const float* w2 = (const float*)d_in[2];
    float* out = (float*)d_out;

    const size_t WT_BYTES     = (size_t)NE * DH * DI * 2;   // 64 MB
    const size_t HIDDEN_BYTES = (size_t)NE * MM * DI * 2;   // 128 MB
    const size_t XB_BYTES     = (size_t)NE * MM * DH * 2;   // 32 MB

    dim3 blk(256), blk512(512);
    if (ws_size >= WT_BYTES + HIDDEN_BYTES + XB_BYTES) {
        unsigned short* wt     = (unsigned short*)d_ws;
        unsigned short* hidden = (unsigned short*)((char*)d_ws + WT_BYTES);
        unsigned short* xb     = (unsigned short*)((char*)d_ws + WT_BYTES + HIDDEN_BYTES);
        const long long nx = (long long)NE * MM * DH;
        convert_bf16<<<dim3((unsigned)(nx / (8 * 256))), blk, 0, stream>>>(x, xb, nx);
        transpose_bf16<<<dim3(DI / 64, DH / 64, NE), blk, 0, stream>>>(w1, wt, DH, DI);
        gemm1_v4<<<dim3(NE * (MM / 256) * (DI / 256)), blk512, 0, stream>>>(xb, wt, hidden);
        transpose_bf16<<<dim3(DH / 64, DI / 64, NE), blk, 0, stream>>>(w2, wt, DI, DH);
        gemm2_v4<<<dim3(NE * (MM / 256) * (DH / 256)), blk512, 0, stream>>>(hidden, wt, out);
    } else if (ws_size >= WT_BYTES + HIDDEN_BYTES) {
        unsigned short* wt     = (unsigned short*)d_ws;
        unsigned short* hidden = (unsigned short*)((char*)d_ws + WT_BYTES);
        transpose_bf16<<<dim3(DI / 64, DH / 64, NE), blk, 0, stream>>>(w1, wt, DH, DI);
        gemm1_mixed<<<dim3(DI / 128, MM / 128, NE), blk, 0, stream>>>(x, wt, hidden);
        transpose_bf16<<<dim3(DH / 64, DI / 64, NE), blk, 0, stream>>>(w2, wt, DI, DH);
        gemm2_v4<<<dim3(NE * (MM / 256) * (DH / 256)), blk512, 0, stream>>>(hidden, wt, out);
    } else {
        unsigned short* hidden = (unsigned short*)d_ws;
        fb_gemm1<<<dim3(DI / 128, MM / 128, NE), blk, 0, stream>>>(x, w1, hidden);
        fb_gemm2<<<dim3(DH / 128, MM / 128, NE), blk, 0, stream>>>(hidden, w2, out);
    }
}

// Round 4
// 617.261 us; speedup vs baseline: 1.0738x; 1.0738x over previous
//
#include <hip/hip_runtime.h>
#include <hip/hip_bf16.h>
#include <math.h>

#define NE 8
#define MM 2048
#define DH 1024   // hidden
#define DI 4096   // intermediate

#define BK  32
#define LDA 40    // padded LDS stride for manually-staged fp32 tiles

typedef short bf16x8 __attribute__((ext_vector_type(8)));
typedef float f32x4  __attribute__((ext_vector_type(4)));

__device__ __forceinline__ unsigned short f2bf(float f) {
    unsigned u = __builtin_bit_cast(unsigned, f);
    u += 0x7FFFu + ((u >> 16) & 1u);   // round-to-nearest-even
    return (unsigned short)(u >> 16);
}

// async global(16B/lane) -> LDS. lds ptr must be wave-uniform base; HW adds lane*16.
__device__ __forceinline__ void gload_lds16(const void* g, void* l) {
    __builtin_amdgcn_global_load_lds(
        (__attribute__((address_space(1))) void*)g,
        (__attribute__((address_space(3))) void*)l, 16, 0, 0);
}

// Fast exact-erf GELU: Abramowitz&Stegun 7.1.26, max abs err 1.5e-7 (<< bf16 ulp).
__device__ __forceinline__ float gelu_fast(float x) {
    float z = fabsf(x) * 0.70710678118654752f;
    float t = __builtin_amdgcn_rcpf(1.0f + 0.3275911f * z);
    float p = t * (0.254829592f + t * (-0.284496736f + t * (1.421413741f +
              t * (-1.453152027f + t * 1.061405429f))));
    float er = 1.0f - p * __expf(-z * z);
    er = (x < 0.0f) ? -er : er;
    return 0.5f * x * (1.0f + er);
}

// ---------------- elementwise fp32 -> bf16 (for X)
__global__ __launch_bounds__(256)
void convert_bf16(const float* __restrict__ in, unsigned short* __restrict__ out,
                  long long n)   // n multiple of 8*256
{
    long long i = ((long long)blockIdx.x * 256 + threadIdx.x) * 8;
    const float4 v0 = *(const float4*)(in + i);
    const float4 v1 = *(const float4*)(in + i + 4);
    bf16x8 s;
    s[0] = (short)f2bf(v0.x); s[1] = (short)f2bf(v0.y);
    s[2] = (short)f2bf(v0.z); s[3] = (short)f2bf(v0.w);
    s[4] = (short)f2bf(v1.x); s[5] = (short)f2bf(v1.y);
    s[6] = (short)f2bf(v1.z); s[7] = (short)f2bf(v1.w);
    *(bf16x8*)(out + i) = s;
}

// ---------------- weight transpose+convert: fp32 [K,N] -> bf16 [N,K], per expert
__global__ __launch_bounds__(256)
void transpose_bf16(const float* __restrict__ in, unsigned short* __restrict__ out,
                    int K, int N)
{
    __shared__ short tile[64][66];
    const int e  = blockIdx.z;
    const int n0 = blockIdx.x * 64;
    const int k0 = blockIdx.y * 64;
    const float* ine = in + (size_t)e * K * N;
    unsigned short* oute = out + (size_t)e * N * K;
    const int tid = threadIdx.x;

    #pragma unroll
    for (int i = 0; i < 4; ++i) {
        int idx = tid + i * 256;
        int r  = idx >> 4;
        int c  = (idx & 15) * 4;
        const float4 v = *(const float4*)(ine + (size_t)(k0 + r) * N + n0 + c);
        tile[r][c + 0] = (short)f2bf(v.x);
        tile[r][c + 1] = (short)f2bf(v.y);
        tile[r][c + 2] = (short)f2bf(v.z);
        tile[r][c + 3] = (short)f2bf(v.w);
    }
    __syncthreads();
    #pragma unroll
    for (int i = 0; i < 4; ++i) {
        int idx = tid + i * 256;
        int n  = idx >> 4;
        int k  = (idx & 15) * 4;
        short4 s;
        s.x = tile[k + 0][n];
        s.y = tile[k + 1][n];
        s.z = tile[k + 2][n];
        s.w = tile[k + 3][n];
        *(short4*)(oute + (size_t)(n0 + n) * K + k0 + k) = s;
    }
}

// ================= v5: 256x256 tile, 512 thr (8 waves 2Mx4N).
// 2 phases per K-tile (32 MFMA each), DEEP-LEAD staging:
//   P0(t): ds B(ks0+ks1)+A(mh0) | stage A(t+1) | bar lgkm0 MFMA32(mh0) bar
//   P1(t): ds A(mh1)            | stage B(t+2) | bar lgkm0 MFMA32(mh1)
//          vmcnt(4)  [outstanding = only B(t+2); A(t+1) lead=2 phases ~1200cy,
//                     B(t+1) lead=3 phases]  | bar
// B-frags held in regs across both phases (24 b128/wave/K-tile minimal).
// vmcnt(0) only in the final iteration. This fixes v3/v4's 1-phase-lead waits
// (each wait blocked on a stage issued ~200cy earlier vs ~900cy HBM latency).

#define VMC(n)  asm volatile("s_waitcnt vmcnt(" #n ")" ::: "memory")
#define LGKM0   do { asm volatile("s_waitcnt lgkmcnt(0)" ::: "memory"); \
                     __builtin_amdgcn_sched_barrier(0); } while (0)
#define BARX    do { __builtin_amdgcn_s_barrier(); \
                     __builtin_amdgcn_sched_barrier(0); } while (0)
#define PRIO1   __builtin_amdgcn_s_setprio(1)
#define PRIO0   __builtin_amdgcn_s_setprio(0)

// stage one full 256x64 bf16 tile t (4 instr/thread). Linear LDS dest,
// inverse-swizzled global source (rule #21; same involution as the reads).
#define STAGE(Ptr, r0, s, t, KD, DstArr)                                       \
    { const size_t kk = (size_t)(t) * 64;                                      \
      _Pragma("unroll")                                                        \
      for (int j = 0; j < 4; ++j) {                                            \
          int idx = tid + j * 512;                                             \
          int row = idx >> 3;                                                  \
          int gs  = (idx & 7) ^ (row & 7);                                     \
          gload_lds16(Ptr + (size_t)((r0) + row) * (KD) + kk + gs * 8,         \
                      &DstArr[s][(j * 512 + wave * 64) * 8]); } }

#define LOAD_B2(s)                                                             \
    _Pragma("unroll")                                                          \
    for (int ni = 0; ni < 4; ++ni)                                             \
        _Pragma("unroll")                                                      \
        for (int ks = 0; ks < 2; ++ks)                                         \
            b[ni][ks] = *(const bf16x8*)(&Bs[s][(wn4 * 64 + ni * 16 + lr) * 64 + \
                          (((ks * 4 + lq) ^ (lr & 7)) * 8)]);

#define LOAD_A2(s, mh)                                                         \
    _Pragma("unroll")                                                          \
    for (int mi = 0; mi < 4; ++mi)                                             \
        _Pragma("unroll")                                                      \
        for (int ks = 0; ks < 2; ++ks)                                         \
            a[mi][ks] = *(const bf16x8*)(&As[s][(wm2 * 128 + (mh) * 64 + mi * 16 + lr) * 64 + \
                          (((ks * 4 + lq) ^ (lr & 7)) * 8)]);

#define MFMA32(mh)                                                             \
    _Pragma("unroll")                                                          \
    for (int mi = 0; mi < 4; ++mi)                                             \
        _Pragma("unroll")                                                      \
        for (int ni = 0; ni < 4; ++ni)                                         \
            _Pragma("unroll")                                                  \
            for (int ks = 0; ks < 2; ++ks)                                     \
                acc[(mh) * 4 + mi][ni] = __builtin_amdgcn_mfma_f32_16x16x32_bf16( \
                    a[mi][ks], b[ni][ks], acc[(mh) * 4 + mi][ni], 0, 0, 0);

#define PIPE_BODY_V5(KD)                                                       \
    __shared__ short As[2][256 * 64];                                          \
    __shared__ short Bs[2][256 * 64];                                          \
    const int tid  = threadIdx.x;                                              \
    const int lane = tid & 63;                                                 \
    const int wave = tid >> 6;                                                 \
    const int wm2  = wave >> 2;                                                \
    const int wn4  = wave & 3;                                                 \
    const int lr   = lane & 15;                                                \
    const int lq   = lane >> 4;                                                \
    const int ITERS = (KD) / 128;   /* 2 K-tiles per iter */                   \
    f32x4 acc[8][4] = {};                                                      \
    bf16x8 a[4][2], b[4][2];                                                   \
    STAGE(Ae, m0, 0, 0, KD, As); STAGE(Be, n0, 0, 0, KD, Bs);                  \
    STAGE(Be, n0, 1, 1, KD, Bs);                                               \
    VMC(4); BARX;                                                              \
    _Pragma("unroll 1")                                                        \
    for (int i = 0; i < ITERS; ++i) {                                          \
        const bool nl = (i < ITERS - 1);                                       \
        /* ---- tile t0 = 2i (buf0) ---- */                                    \
        /* P0(t0) */                                                           \
        LOAD_B2(0); LOAD_A2(0, 0);                                             \
        STAGE(Ae, m0, 1, 2 * i + 1, KD, As);      /* A(t0+1) -> buf1 */        \
        BARX; LGKM0; PRIO1; MFMA32(0); PRIO0; BARX;                            \
        /* P1(t0) */                                                           \
        LOAD_A2(0, 1);                                                         \
        if (nl) STAGE(Be, n0, 0, 2 * i + 2, KD, Bs);  /* B(t0+2) -> buf0 */    \
        BARX; LGKM0; PRIO1; MFMA32(1); PRIO0;                                  \
        if (nl) { VMC(4); } else { VMC(0); }                                   \
        BARX;                                                                  \
        /* ---- tile t1 = 2i+1 (buf1) ---- */                                  \
        /* P0(t1) */                                                           \
        LOAD_B2(1); LOAD_A2(1, 0);                                             \
        if (nl) STAGE(Ae, m0, 0, 2 * i + 2, KD, As);  /* A(t1+1) -> buf0 */    \
        BARX; LGKM0; PRIO1; MFMA32(0); PRIO0; BARX;                            \
        /* P1(t1) */                                                           \
        LOAD_A2(1, 1);                                                         \
        if (nl) STAGE(Be, n0, 1, 2 * i + 3, KD, Bs);  /* B(t1+2) -> buf1 */    \
        BARX; LGKM0; PRIO1; MFMA32(1); PRIO0;                                  \
        if (nl) VMC(4);                                                        \
        BARX;                                                                  \
    }

// XCD-bijective chunked swizzle, m-fastest within expert (1 expert/XCD).
#define DECOMPOSE_XCD_V3(TPE)                                                  \
    const int bsw  = (blockIdx.x & 7) * (TPE) + (blockIdx.x >> 3);             \
    const int e    = bsw / (TPE);                                              \
    const int trem = bsw - e * (TPE);                                          \
    const int m0   = (trem & 7) * 256;                                         \
    const int n0   = (trem >> 3) * 256;

// GEMM1: H = gelu_erf(Xb @ W1t^T); Xb bf16 [M,DH], W1t bf16 [DI,DH], H bf16 [M,DI]
__global__ __launch_bounds__(512, 2)
void gemm1_v5(const unsigned short* __restrict__ Xb,
              const unsigned short* __restrict__ W1t,
              unsigned short* __restrict__ H)
{
    DECOMPOSE_XCD_V3(128)
    const unsigned short* Ae = Xb  + (size_t)e * MM * DH;
    const unsigned short* Be = W1t + (size_t)e * DI * DH;
    unsigned short* He = H + (size_t)e * MM * DI;

    PIPE_BODY_V5(DH)

    #pragma unroll
    for (int mi = 0; mi < 8; ++mi) {
        #pragma unroll
        for (int ni = 0; ni < 4; ++ni) {
            const int col = n0 + wn4 * 64 + ni * 16 + lr;
            #pragma unroll
            for (int r = 0; r < 4; ++r) {
                const int row = m0 + wm2 * 128 + mi * 16 + lq * 4 + r;
                He[(size_t)row * DI + col] = f2bf(gelu_fast(acc[mi][ni][r]));
            }
        }
    }
}

// GEMM2: O = H @ W2t^T; H bf16 [M,DI], W2t bf16 [DH,DI], O fp32 [M,DH]
__global__ __launch_bounds__(512, 2)
void gemm2_v5(const unsigned short* __restrict__ H,
              const unsigned short* __restrict__ W2t,
              float* __restrict__ O)
{
    DECOMPOSE_XCD_V3(32)
    const unsigned short* Ae = H   + (size_t)e * MM * DI;
    const unsigned short* Be = W2t + (size_t)e * DH * DI;
    float* Oe = O + (size_t)e * MM * DH;

    PIPE_BODY_V5(DI)

    #pragma unroll
    for (int mi = 0; mi < 8; ++mi) {
        #pragma unroll
        for (int ni = 0; ni < 4; ++ni) {
            const int col = n0 + wn4 * 64 + ni * 16 + lr;
            #pragma unroll
            for (int r = 0; r < 4; ++r) {
                const int row = m0 + wm2 * 128 + mi * 16 + lq * 4 + r;
                Oe[(size_t)row * DH + col] = acc[mi][ni][r];
            }
        }
    }
}

// ---------------- mid-tier gemm1 (fp32 X manually staged)
__global__ __launch_bounds__(256, 2)
void gemm1_mixed(const float* __restrict__ X, const unsigned short* __restrict__ W1t,
                 unsigned short* __restrict__ H)
{
    __shared__ short As[128 * LDA];
    __shared__ short Bs[128 * 32];
    const int e  = blockIdx.z;
    const int m0 = blockIdx.y * 128;
    const int n0 = blockIdx.x * 128;
    const float* Xe = X + (size_t)e * MM * DH;
    const unsigned short* Bt = W1t + (size_t)e * DI * DH;
    unsigned short* He = H + (size_t)e * MM * DI;
    const int tid  = threadIdx.x;
    const int lane = tid & 63;
    const int wave = tid >> 6;
    const int wm = (wave >> 1) * 64;
    const int wn = (wave &  1) * 64;
    const int lr = lane & 15;
    const int lq = lane >> 4;
    f32x4 acc[4][4] = {};
    for (int k0 = 0; k0 < DH; k0 += BK) {
        #pragma unroll
        for (int i = 0; i < 2; ++i) {
            int idx  = tid + i * 256;
            gload_lds16(Bt + (size_t)(n0 + (idx >> 2)) * DH + k0 + (idx & 3) * 8,
                        Bs + (i * 256 + wave * 64) * 8);
        }
        #pragma unroll
        for (int i = 0; i < 4; ++i) {
            int idx = tid + i * 256;
            int row = idx >> 3;
            int col = (idx & 7) * 4;
            const float4 v = *(const float4*)(Xe + (size_t)(m0 + row) * DH + k0 + col);
            short4 s;
            s.x = (short)f2bf(v.x); s.y = (short)f2bf(v.y);
            s.z = (short)f2bf(v.z); s.w = (short)f2bf(v.w);
            *(short4*)(&As[row * LDA + col]) = s;
        }
        __syncthreads();
        bf16x8 a[4], b[4];
        #pragma unroll
        for (int i = 0; i < 4; ++i)
            a[i] = *(const bf16x8*)(&As[(wm + i * 16 + lr) * LDA + lq * 8]);
        #pragma unroll
        for (int i = 0; i < 4; ++i)
            b[i] = *(const bf16x8*)(&Bs[(wn + i * 16 + lr) * 32 + lq * 8]);
        #pragma unroll
        for (int mi = 0; mi < 4; ++mi)
            #pragma unroll
            for (int ni = 0; ni < 4; ++ni)
                acc[mi][ni] = __builtin_amdgcn_mfma_f32_16x16x32_bf16(a[mi], b[ni], acc[mi][ni], 0, 0, 0);
        __syncthreads();
    }
    #pragma unroll
    for (int mi = 0; mi < 4; ++mi) {
        #pragma unroll
        for (int ni = 0; ni < 4; ++ni) {
            const int col = n0 + wn + ni * 16 + lr;
            #pragma unroll
            for (int r = 0; r < 4; ++r) {
                const int row = m0 + wm + mi * 16 + lq * 4 + r;
                He[(size_t)row * DI + col] = f2bf(gelu_fast(acc[mi][ni][r]));
            }
        }
    }
}

// ================= round-1 fallback (needs only 128MB ws) =================
__global__ __launch_bounds__(256, 2)
void fb_gemm1(const float* __restrict__ X, const float* __restrict__ W1,
              unsigned short* __restrict__ H)
{
    __shared__ short As[128 * LDA];
    __shared__ short Bs[128 * LDA];
    const int e  = blockIdx.z;
    const int m0 = blockIdx.y * 128;
    const int n0 = blockIdx.x * 128;
    const float* Xe  = X  + (size_t)e * MM * DH;
    const float* W1e = W1 + (size_t)e * DH * DI;
    unsigned short* He = H + (size_t)e * MM * DI;
    const int tid  = threadIdx.x;
    const int lane = tid & 63;
    const int wave = tid >> 6;
    const int wm = (wave >> 1) * 64;
    const int wn = (wave &  1) * 64;
    const int lr = lane & 15;
    const int lq = lane >> 4;
    f32x4 acc[4][4] = {};
    for (int k0 = 0; k0 < DH; k0 += BK) {
        #pragma unroll
        for (int i = 0; i < 4; ++i) {
            int idx = tid + i * 256;
            int row = idx >> 3;
            int col = (idx & 7) * 4;
            const float4 v = *(const float4*)(Xe + (size_t)(m0 + row) * DH + k0 + col);
            short4 s;
            s.x = (short)f2bf(v.x); s.y = (short)f2bf(v.y);
            s.z = (short)f2bf(v.z); s.w = (short)f2bf(v.w);
            *(short4*)(&As[row * LDA + col]) = s;
        }
        #pragma unroll
        for (int i = 0; i < 4; ++i) {
            int idx  = tid + i * 256;
            int krow = idx >> 5;
            int ncol = (idx & 31) * 4;
            const float4 v = *(const float4*)(W1e + (size_t)(k0 + krow) * DI + n0 + ncol);
            Bs[(ncol + 0) * LDA + krow] = (short)f2bf(v.x);
            Bs[(ncol + 1) * LDA + krow] = (short)f2bf(v.y);
            Bs[(ncol + 2) * LDA + krow] = (short)f2bf(v.z);
            Bs[(ncol + 3) * LDA + krow] = (short)f2bf(v.w);
        }
        __syncthreads();
        bf16x8 a[4], b[4];
        #pragma unroll
        for (int i = 0; i < 4; ++i)
            a[i] = *(const bf16x8*)(&As[(wm + i * 16 + lr) * LDA + lq * 8]);
        #pragma unroll
        for (int i = 0; i < 4; ++i)
            b[i] = *(const bf16x8*)(&Bs[(wn + i * 16 + lr) * LDA + lq * 8]);
        #pragma unroll
        for (int mi = 0; mi < 4; ++mi)
            #pragma unroll
            for (int ni = 0; ni < 4; ++ni)
                acc[mi][ni] = __builtin_amdgcn_mfma_f32_16x16x32_bf16(a[mi], b[ni], acc[mi][ni], 0, 0, 0);
        __syncthreads();
    }
    #pragma unroll
    for (int mi = 0; mi < 4; ++mi) {
        #pragma unroll
        for (int ni = 0; ni < 4; ++ni) {
            const int col = n0 + wn + ni * 16 + lr;
            #pragma unroll
            for (int r = 0; r < 4; ++r) {
                const int row = m0 + wm + mi * 16 + lq * 4 + r;
                He[(size_t)row * DI + col] = f2bf(gelu_fast(acc[mi][ni][r]));
            }
        }
    }
}

__global__ __launch_bounds__(256, 2)
void fb_gemm2(const unsigned short* __restrict__ H, const float* __restrict__ W2,
              float* __restrict__ O)
{
    __shared__ short As[128 * LDA];
    __shared__ short Bs[128 * LDA];
    const int e  = blockIdx.z;
    const int m0 = blockIdx.y * 128;
    const int n0 = blockIdx.x * 128;
    const unsigned short* He = H + (size_t)e * MM * DI;
    const float* W2e = W2 + (size_t)e * DI * DH;
    float* Oe = O + (size_t)e * MM * DH;
    const int tid  = threadIdx.x;
    const int lane = tid & 63;
    const int wave = tid >> 6;
    const int wm = (wave >> 1) * 64;
    const int wn = (wave &  1) * 64;
    const int lr = lane & 15;
    const int lq = lane >> 4;
    f32x4 acc[4][4] = {};
    for (int k0 = 0; k0 < DI; k0 += BK) {
        #pragma unroll
        for (int i = 0; i < 2; ++i) {
            int idx = tid + i * 256;
            int row = idx >> 2;
            int col = (idx & 3) * 8;
            bf16x8 v = *(const bf16x8*)(He + (size_t)(m0 + row) * DI + k0 + col);
            *(bf16x8*)(&As[row * LDA + col]) = v;
        }
        #pragma unroll
        for (int i = 0; i < 4; ++i) {
            int idx  = tid + i * 256;
            int krow = idx >> 5;
            int ncol = (idx & 31) * 4;
            const float4 v = *(const float4*)(W2e + (size_t)(k0 + krow) * DH + n0 + ncol);
            Bs[(ncol + 0) * LDA + krow] = (short)f2bf(v.x);
            Bs[(ncol + 1) * LDA + krow] = (short)f2bf(v.y);
            Bs[(ncol + 2) * LDA + krow] = (short)f2bf(v.z);
            Bs[(ncol + 3) * LDA + krow] = (short)f2bf(v.w);
        }
        __syncthreads();
        bf16x8 a[4], b[4];
        #pragma unroll
        for (int i = 0; i < 4; ++i)
            a[i] = *(const bf16x8*)(&As[(wm + i * 16 + lr) * LDA + lq * 8]);
        #pragma unroll
        for (int i = 0; i < 4; ++i)
            b[i] = *(const bf16x8*)(&Bs[(wn + i * 16 + lr) * LDA + lq * 8]);
        #pragma unroll
        for (int mi = 0; mi < 4; ++mi)
            #pragma unroll
            for (int ni = 0; ni < 4; ++ni)
                acc[mi][ni] = __builtin_amdgcn_mfma_f32_16x16x32_bf16(a[mi], b[ni], acc[mi][ni], 0, 0, 0);
        __syncthreads();
    }
    #pragma unroll
    for (int mi = 0; mi < 4; ++mi) {
        #pragma unroll
        for (int ni = 0; ni < 4; ++ni) {
            const int col = n0 + wn + ni * 16 + lr;
            #pragma unroll
            for (int r = 0; r < 4; ++r) {
                const int row = m0 + wm + mi * 16 + lq * 4 + r;
                Oe[(size_t)row * DH + col] = acc[mi][ni][r];
            }
        }
    }
}

extern "C" void kernel_launch(void* const* d_in, const int* in_sizes, int n_in,
                              void* d_out, int out_size, void* d_ws, size_t ws_size,
                              hipStream_t stream) {
    const float* x  = (const float*)d_in[0];
    const float* w1 = (const float*)d_in[1];
    const float* w2 = (const float*)d_in[2];
    float* out = (float*)d_out;

    const size_t WT_BYTES     = (size_t)NE * DH * DI * 2;   // 64 MB
    const size_t HIDDEN_BYTES = (size_t)NE * MM * DI * 2;   // 128 MB
    const size_t XB_BYTES     = (size_t)NE * MM * DH * 2;   // 32 MB

    dim3 blk(256), blk512(512);
    if (ws_size >= WT_BYTES + HIDDEN_BYTES + XB_BYTES) {
        unsigned short* wt     = (unsigned short*)d_ws;
        unsigned short* hidden = (unsigned short*)((char*)d_ws + WT_BYTES);
        unsigned short* xb     = (unsigned short*)((char*)d_ws + WT_BYTES + HIDDEN_BYTES);
        const long long nx = (long long)NE * MM * DH;
        convert_bf16<<<dim3((unsigned)(nx / (8 * 256))), blk, 0, stream>>>(x, xb, nx);
        transpose_bf16<<<dim3(DI / 64, DH / 64, NE), blk, 0, stream>>>(w1, wt, DH, DI);
        gemm1_v5<<<dim3(NE * (MM / 256) * (DI / 256)), blk512, 0, stream>>>(xb, wt, hidden);
        transpose_bf16<<<dim3(DH / 64, DI / 64, NE), blk, 0, stream>>>(w2, wt, DI, DH);
        gemm2_v5<<<dim3(NE * (MM / 256) * (DH / 256)), blk512, 0, stream>>>(hidden, wt, out);
    } else if (ws_size >= WT_BYTES + HIDDEN_BYTES) {
        unsigned short* wt     = (unsigned short*)d_ws;
        unsigned short* hidden = (unsigned short*)((char*)d_ws + WT_BYTES);
        transpose_bf16<<<dim3(DI / 64, DH / 64, NE), blk, 0, stream>>>(w1, wt, DH, DI);
        gemm1_mixed<<<dim3(DI / 128, MM / 128, NE), blk, 0, stream>>>(x, wt, hidden);
        transpose_bf16<<<dim3(DH / 64, DI / 64, NE), blk, 0, stream>>>(w2, wt, DI, DH);
        gemm2_v5<<<dim3(NE * (MM / 256) * (DH / 256)), blk512, 0, stream>>>(hidden, wt, out);
    } else {
        unsigned short* hidden = (unsigned short*)d_ws;
        fb_gemm1<<<dim3(DI / 128, MM / 128, NE), blk, 0, stream>>>(x, w1, hidden);
        fb_gemm2<<<dim3(DH / 128, MM / 128, NE), blk, 0, stream>>>(hidden, w2, out);
    }
}